// Round 4
// baseline (9987.326 us; speedup 1.0000x reference)
//
#include <hip/hip_runtime.h>
#include <hip/hip_cooperative_groups.h>
#include <math.h>

namespace cg = cooperative_groups;

#define NFULL 2177   // 1 + L + S
#define NN    2176   // minor size (NFULL-1), = 34*64
#define NB    64
#define NMAT  8      // 4 batches x {z, target}
#define NBATCH 4
#define TP    65     // pitch of 64x64 factor/inverse tiles in LDS
#define LTP   132    // Lt quarter pitch (128 rows + pad)
#define UTP   188    // Ut quarter pitch (128 cols + 4-per-8 skew)
#define QL    (16 * LTP)          // 2112 floats
#define QU    (16 * UTP)          // 3008 floats
#define QBUF  (QL + QU)           // 5120 floats per quarter buffer
#define SSZ2  (2 * QBUF)          // 10240 floats = 40 KB

// ---------------- LU building blocks (identical math to round 3) ----------------

// Factor 64x64 block in LDS (pitch TP), L unit-lower \ U upper. 256 threads.
__device__ __forceinline__ void factor64(float* T, int tid) {
  int c = tid & 63, g = tid >> 6;
  for (int j = 0; j < 63; ++j) {
    float inv = 1.0f / T[j * TP + j];
    int rs = j + 1 + ((g - j - 1) & 3);
    if (c == j) {
      for (int r = rs; r < 64; r += 4) T[r * TP + j] *= inv;
    }
    __syncthreads();
    if (c > j) {
      float ujc = T[j * TP + c];
      for (int r = rs; r < 64; r += 4) T[r * TP + c] -= T[r * TP + j] * ujc;
    }
    __syncthreads();
  }
}

// Parallel blocked inversion of L (unit-lower) and U from factored T (pitch TP).
__device__ void invert64(const float* T, float* X,
                         float* __restrict__ invUg,
                         float* __restrict__ invLg, int tid) {
  if (tid < 64) {
    int o = (tid >> 5) * 32, jj = tid & 31, j = o + jj;
    X[(o + jj) * TP + j] = 1.0f / T[(o + jj) * TP + (o + jj)];
    for (int i = jj - 1; i >= 0; --i) {
      float s = 0.f;
      for (int t = i + 1; t <= jj; ++t)
        s += T[(o + i) * TP + (o + t)] * X[(o + t) * TP + j];
      X[(o + i) * TP + j] = -s / T[(o + i) * TP + (o + i)];
    }
  }
  __syncthreads();
  for (int e = tid; e < 1024; e += 256) {
    int i = e >> 5, j = e & 31;
    float s = 0.f;
    for (int t = 0; t <= j; ++t)
      s += T[i * TP + 32 + t] * X[(32 + t) * TP + 32 + j];
    X[(32 + i) * TP + j] = s;
  }
  __syncthreads();
  for (int e = tid; e < 1024; e += 256) {
    int i = e >> 5, j = e & 31;
    float s = 0.f;
    for (int t = i; t < 32; ++t)
      s += X[i * TP + t] * X[(32 + t) * TP + j];
    X[i * TP + 32 + j] = -s;
  }
  __syncthreads();
  for (int e = tid; e < 4096; e += 256) {
    int i = e >> 6, j = e & 63;
    float v = 0.f;
    if (i < 32 && j >= 32) v = X[i * TP + j];
    else if ((i >> 5) == (j >> 5) && i <= j) v = X[i * TP + j];
    invUg[e] = v;
  }
  __syncthreads();
  if (tid < 64) {
    int o = (tid >> 5) * 32, jj = tid & 31, j = o + jj;
    X[(o + jj) * TP + j] = 1.0f;
    for (int i = jj + 1; i < 32; ++i) {
      float s = 0.f;
      for (int t = jj; t < i; ++t)
        s += T[(o + i) * TP + (o + t)] * X[(o + t) * TP + j];
      X[(o + i) * TP + j] = -s;
    }
  }
  __syncthreads();
  for (int e = tid; e < 1024; e += 256) {
    int i = e >> 5, j = e & 31;
    float s = 0.f;
    for (int t = j; t < 32; ++t)
      s += T[(32 + i) * TP + t] * X[t * TP + j];
    X[i * TP + 32 + j] = s;
  }
  __syncthreads();
  for (int e = tid; e < 1024; e += 256) {
    int i = e >> 5, j = e & 31;
    float s = 0.f;
    for (int t = 0; t <= i; ++t)
      s += X[(32 + i) * TP + 32 + t] * X[t * TP + 32 + j];
    X[(32 + i) * TP + j] = -s;
  }
  __syncthreads();
  for (int e = tid; e < 4096; e += 256) {
    int i = e >> 6, j = e & 63;
    float v = 0.f;
    if (i >= 32 && j < 32) v = X[i * TP + j];
    else if ((i >> 5) == (j >> 5)) v = (i > j) ? X[i * TP + j] : (i == j ? 1.f : 0.f);
    invLg[e] = v;
  }
}

// Panel tile: role 0 -> L21 = A21 * invU ; role 1 -> U12 = invL * A12
__device__ void panel_job(float* __restrict__ Mb, const float* __restrict__ invUb,
                          const float* __restrict__ invLb, int k0,
                          int m, int role, int px, int tid, float* S) {
  float* Aa = S;            // [64][68], Aa[k][r]
  float* Bb = S + 64 * 68;  // [64][68], Bb[k][c]
  float* A = Mb + (size_t)m * NN * NN;
  int obase = k0 + 64 + px * 64;
  if (role == 0) {
    const float* iU = invUb + (size_t)m * 4096;
    for (int idx = tid; idx < 4096; idx += 256) {
      int r = idx >> 6, k = idx & 63;
      Aa[k * 68 + r] = A[(size_t)(obase + r) * NN + (k0 + k)];
    }
    for (int idx = tid; idx < 4096; idx += 256)
      Bb[(idx >> 6) * 68 + (idx & 63)] = iU[idx];
  } else {
    const float* iL = invLb + (size_t)m * 4096;
    for (int idx = tid; idx < 4096; idx += 256) {
      int r = idx >> 6, k = idx & 63;
      Aa[k * 68 + r] = iL[(r << 6) + k];
    }
    for (int idx = tid; idx < 4096; idx += 256) {
      int k = idx >> 6, c = idx & 63;
      Bb[k * 68 + c] = A[(size_t)(k0 + k) * NN + (obase + c)];
    }
  }
  __syncthreads();
  int c0 = (tid & 15) << 2;
  int r0 = (tid >> 4) << 2;
  float acc[4][4];
#pragma unroll
  for (int i = 0; i < 4; ++i)
#pragma unroll
    for (int jj = 0; jj < 4; ++jj) acc[i][jj] = 0.f;
#pragma unroll 8
  for (int k = 0; k < 64; ++k) {
    float4 a  = *(const float4*)&Aa[k * 68 + r0];
    float4 bv = *(const float4*)&Bb[k * 68 + c0];
    acc[0][0] += a.x * bv.x; acc[0][1] += a.x * bv.y; acc[0][2] += a.x * bv.z; acc[0][3] += a.x * bv.w;
    acc[1][0] += a.y * bv.x; acc[1][1] += a.y * bv.y; acc[1][2] += a.y * bv.z; acc[1][3] += a.y * bv.w;
    acc[2][0] += a.z * bv.x; acc[2][1] += a.z * bv.y; acc[2][2] += a.z * bv.z; acc[2][3] += a.z * bv.w;
    acc[3][0] += a.w * bv.x; acc[3][1] += a.w * bv.y; acc[3][2] += a.w * bv.z; acc[3][3] += a.w * bv.w;
  }
  if (role == 0) {
#pragma unroll
    for (int i = 0; i < 4; ++i) {
      float4 v = make_float4(acc[i][0], acc[i][1], acc[i][2], acc[i][3]);
      *(float4*)&A[(size_t)(obase + r0 + i) * NN + (k0 + c0)] = v;
    }
  } else {
#pragma unroll
    for (int i = 0; i < 4; ++i) {
      float4 v = make_float4(acc[i][0], acc[i][1], acc[i][2], acc[i][3]);
      *(float4*)&A[(size_t)(k0 + r0 + i) * NN + (obase + c0)] = v;
    }
  }
}

// ---- trail staging helpers (reg-staged, software-pipelined) ----

__device__ __forceinline__ void load_quarter_regs(const float* __restrict__ A,
                                                  int rbase, int cbase, int rows, int cols,
                                                  int kb, float* lr, float* ur, int tid) {
#pragma unroll
  for (int s = 0; s < 8; ++s) {
    int idx = tid + s * 256;
    int k = idx & 15, r = idx >> 4;
    int gr = rbase + (r < rows ? r : 0);
    lr[s] = A[(size_t)gr * NN + kb + k];
  }
#pragma unroll
  for (int s = 0; s < 8; ++s) {
    int idx = tid + s * 256;
    int c = idx & 127, k = idx >> 7;
    int gc = cbase + (c < cols ? c : 0);
    ur[s] = A[(size_t)(kb + k) * NN + gc];
  }
}

__device__ __forceinline__ void write_quarter_lds(float* __restrict__ S,
                                                  const float* lr, const float* ur, int tid) {
#pragma unroll
  for (int s = 0; s < 8; ++s) {
    int idx = tid + s * 256;
    int k = idx & 15, r = idx >> 4;
    S[k * LTP + r] = lr[s];
  }
#pragma unroll
  for (int s = 0; s < 8; ++s) {
    int idx = tid + s * 256;
    int c = idx & 127, k = idx >> 7;
    S[QL + k * UTP + c + 4 * (c >> 3)] = ur[s];
  }
}

// Trailing-update tile 128x128, 8x8 micro, K=64 in four pipelined quarters.
// Special tile (ty==tx==0): also factor next diagonal block + inverses.
__device__ void trail_job(float* __restrict__ Mb, float* __restrict__ invUb,
                          float* __restrict__ invLb, int k0, int remm,
                          int m, int tyt, int txt, int do_inv, int tid, float* S) {
  float* A = Mb + (size_t)m * NN * NN;
  int base = k0 + NB;
  int rbase = base + tyt * 128, cbase = base + txt * 128;
  int rows = remm - tyt * 128; if (rows > 128) rows = 128;
  int cols = remm - txt * 128; if (cols > 128) cols = 128;
  int tx = tid & 15, ty = tid >> 4;
  int rr = ty * 8, cc = tx * 8;
  int ccs = 12 * tx;            // skewed Ut offset: cc + 4*(cc>>3)
  float acc[8][8];
#pragma unroll
  for (int i = 0; i < 8; ++i)
#pragma unroll
    for (int j = 0; j < 8; ++j) acc[i][j] = 0.f;

  float lr[8], ur[8];
  load_quarter_regs(A, rbase, cbase, rows, cols, k0, lr, ur, tid);
  write_quarter_lds(S, lr, ur, tid);
  __syncthreads();

#pragma unroll
  for (int q = 0; q < 4; ++q) {
    if (q < 3)
      load_quarter_regs(A, rbase, cbase, rows, cols, k0 + (q + 1) * 16, lr, ur, tid);
    const float* Sc = S + (q & 1) * QBUF;
#pragma unroll
    for (int k = 0; k < 16; ++k) {
      const float* lp = &Sc[k * LTP + rr];
      const float* up = &Sc[QL + k * UTP + ccs];
      float4 a0 = *(const float4*)lp;
      float4 a1 = *(const float4*)(lp + 4);
      float4 b0 = *(const float4*)up;
      float4 b1 = *(const float4*)(up + 4);
      acc[0][0] += a0.x * b0.x; acc[0][1] += a0.x * b0.y; acc[0][2] += a0.x * b0.z; acc[0][3] += a0.x * b0.w;
      acc[0][4] += a0.x * b1.x; acc[0][5] += a0.x * b1.y; acc[0][6] += a0.x * b1.z; acc[0][7] += a0.x * b1.w;
      acc[1][0] += a0.y * b0.x; acc[1][1] += a0.y * b0.y; acc[1][2] += a0.y * b0.z; acc[1][3] += a0.y * b0.w;
      acc[1][4] += a0.y * b1.x; acc[1][5] += a0.y * b1.y; acc[1][6] += a0.y * b1.z; acc[1][7] += a0.y * b1.w;
      acc[2][0] += a0.z * b0.x; acc[2][1] += a0.z * b0.y; acc[2][2] += a0.z * b0.z; acc[2][3] += a0.z * b0.w;
      acc[2][4] += a0.z * b1.x; acc[2][5] += a0.z * b1.y; acc[2][6] += a0.z * b1.z; acc[2][7] += a0.z * b1.w;
      acc[3][0] += a0.w * b0.x; acc[3][1] += a0.w * b0.y; acc[3][2] += a0.w * b0.z; acc[3][3] += a0.w * b0.w;
      acc[3][4] += a0.w * b1.x; acc[3][5] += a0.w * b1.y; acc[3][6] += a0.w * b1.z; acc[3][7] += a0.w * b1.w;
      acc[4][0] += a1.x * b0.x; acc[4][1] += a1.x * b0.y; acc[4][2] += a1.x * b0.z; acc[4][3] += a1.x * b0.w;
      acc[4][4] += a1.x * b1.x; acc[4][5] += a1.x * b1.y; acc[4][6] += a1.x * b1.z; acc[4][7] += a1.x * b1.w;
      acc[5][0] += a1.y * b0.x; acc[5][1] += a1.y * b0.y; acc[5][2] += a1.y * b0.z; acc[5][3] += a1.y * b0.w;
      acc[5][4] += a1.y * b1.x; acc[5][5] += a1.y * b1.y; acc[5][6] += a1.y * b1.z; acc[5][7] += a1.y * b1.w;
      acc[6][0] += a1.z * b0.x; acc[6][1] += a1.z * b0.y; acc[6][2] += a1.z * b0.z; acc[6][3] += a1.z * b0.w;
      acc[6][4] += a1.z * b1.x; acc[6][5] += a1.z * b1.y; acc[6][6] += a1.z * b1.z; acc[6][7] += a1.z * b1.w;
      acc[7][0] += a1.w * b0.x; acc[7][1] += a1.w * b0.y; acc[7][2] += a1.w * b0.z; acc[7][3] += a1.w * b0.w;
      acc[7][4] += a1.w * b1.x; acc[7][5] += a1.w * b1.y; acc[7][6] += a1.w * b1.z; acc[7][7] += a1.w * b1.w;
    }
    __syncthreads();
    if (q < 3) {
      write_quarter_lds(S + ((q + 1) & 1) * QBUF, lr, ur, tid);
      __syncthreads();
    }
  }

  bool special = (txt == 0 && tyt == 0);
  if (!special) {
    if (cc < cols) {
#pragma unroll
      for (int i = 0; i < 8; ++i) {
        int r = rr + i;
        if (r < rows) {
          float4* p = (float4*)&A[(size_t)(rbase + r) * NN + cbase + cc];
          float4 v0 = p[0], v1 = p[1];
          v0.x -= acc[i][0]; v0.y -= acc[i][1]; v0.z -= acc[i][2]; v0.w -= acc[i][3];
          v1.x -= acc[i][4]; v1.y -= acc[i][5]; v1.z -= acc[i][6]; v1.w -= acc[i][7];
          p[0] = v0; p[1] = v1;
        }
      }
    }
    return;
  }
  // special: top-left 64x64 quadrant IS the next diagonal block
  float* T = S;            // 64x64, pitch TP
  float* X = S + 4224;     // 64x64, pitch TP
  if (cc < cols) {
#pragma unroll
    for (int i = 0; i < 8; ++i) {
      int r = rr + i;
      if (r < rows) {
        float4* p = (float4*)&A[(size_t)(rbase + r) * NN + cbase + cc];
        float4 v0 = p[0], v1 = p[1];
        v0.x -= acc[i][0]; v0.y -= acc[i][1]; v0.z -= acc[i][2]; v0.w -= acc[i][3];
        v1.x -= acc[i][4]; v1.y -= acc[i][5]; v1.z -= acc[i][6]; v1.w -= acc[i][7];
        if (r < 64 && cc < 64) {
          float* t = &T[r * TP + cc];
          t[0] = v0.x; t[1] = v0.y; t[2] = v0.z; t[3] = v0.w;
          t[4] = v1.x; t[5] = v1.y; t[6] = v1.z; t[7] = v1.w;
        } else {
          p[0] = v0; p[1] = v1;
        }
      }
    }
  }
  __syncthreads();
  factor64(T, tid);
  for (int idx = tid; idx < 4096; idx += 256) {
    int r = idx >> 6, c = idx & 63;
    A[(size_t)(base + r) * NN + base + c] = T[r * TP + c];
  }
  if (do_inv)
    invert64(T, X, invUb + (size_t)m * 4096, invLb + (size_t)m * 4096, tid);
}

// ---------------- the persistent cooperative kernel ----------------

__global__ __launch_bounds__(256, 3) void lu_coop(const float* __restrict__ scores,
                                                  const float* __restrict__ zm,
                                                  const float* __restrict__ tm,
                                                  const int* __restrict__ lengths,
                                                  float* __restrict__ M,
                                                  float* __restrict__ cs,
                                                  float* __restrict__ invU,
                                                  float* __restrict__ invL) {
  __shared__ float S[SSZ2];
  cg::grid_group grid = cg::this_grid();
  const int tid = threadIdx.x;
  const int bid = blockIdx.x;
  const int G = gridDim.x;

  // per-matrix active minor size, rounded up to 64 (pad region stays identity)
  int nmr[NMAT];
#pragma unroll
  for (int mm = 0; mm < NMAT; ++mm) {
    int nm = lengths[mm & 3] - 1;
    nm = (nm + 63) & ~63;
    if (nm < 64) nm = 64;
    if (nm > NN) nm = NN;
    nmr[mm] = nm;
  }

  // phase 0: zero column sums
  for (int i = bid * 256 + tid; i < NMAT * NN; i += G * 256) cs[i] = 0.f;
  grid.sync();

  // phase 1: build off-diagonals + column sums (single pass over inputs)
  for (int job = bid; job < 9 * 34 * NBATCH; job += G) {
    int b = job / (9 * 34);
    int rj = job - b * (9 * 34);
    int ry = rj / 9, cx = rj - ry * 9;
    int c = cx * 256 + tid;
    if (c < NN) {
      int len = lengths[b];
      int j = c + 1;
      bool jv = (j < len);
      int r0 = ry * 64;
      size_t sbase = (size_t)b * NFULL * NFULL + j;
      float az = 0.f, at = 0.f;
      if (ry == 0 && jv) {
        float e = __expf(scores[sbase]);
        az += e * zm[sbase];
        at += e * tm[sbase];
      }
      size_t mz = (size_t)b * NN * NN + (size_t)r0 * NN + c;
      size_t mt = (size_t)(NBATCH + b) * NN * NN + (size_t)r0 * NN + c;
      for (int rrr = 0; rrr < 64; ++rrr) {
        int i = r0 + rrr + 1;
        float vz = 0.f, vt = 0.f;
        if (jv && i < len) {
          size_t off = sbase + (size_t)i * NFULL;
          float e = __expf(scores[off]);
          vz = e * zm[off];
          vt = e * tm[off];
          az += vz;
          at += vt;
        }
        M[mz] = -vz;
        M[mt] = -vt;
        mz += NN;
        mt += NN;
      }
      if (az != 0.f) atomicAdd(&cs[b * NN + c], az);
      if (at != 0.f) atomicAdd(&cs[(NBATCH + b) * NN + c], at);
    }
  }
  grid.sync();

  // phase 2: diagonal = colsum + pad
  for (int i = bid * 256 + tid; i < NMAT * NN; i += G * 256) {
    int mm = i / NN, c = i - mm * NN;
    int len = lengths[mm & 3];
    float pad = (c + 1 < len) ? 0.f : 1.f;
    M[(size_t)mm * NN * NN + (size_t)c * NN + c] = cs[i] + pad;
  }
  grid.sync();

  // phase 3: factor + invert diagonal block 0
  if (bid < NMAT) {
    float* A = M + (size_t)bid * NN * NN;
    for (int idx = tid; idx < 4096; idx += 256)
      S[(idx >> 6) * TP + (idx & 63)] = A[(size_t)(idx >> 6) * NN + (idx & 63)];
    __syncthreads();
    factor64(S, tid);
    for (int idx = tid; idx < 4096; idx += 256)
      A[(size_t)(idx >> 6) * NN + (idx & 63)] = S[(idx >> 6) * TP + (idx & 63)];
    invert64(S, S + 4224, invU + (size_t)bid * 4096, invL + (size_t)bid * 4096, tid);
  }
  grid.sync();

  // LU loop: 33 iterations, 2 grid syncs each
  for (int k0 = 0; k0 + NB < NN; k0 += NB) {
    // ---- panel phase ----
    int totA = 0;
#pragma unroll
    for (int mm = 0; mm < NMAT; ++mm) {
      int remm = nmr[mm] - k0 - NB;
      if (remm > 0) totA += 2 * (remm >> 6);
    }
    for (int job = bid; job < totA; job += G) {
      int m = 0, local = 0, bbase = 0;
#pragma unroll
      for (int mm = 0; mm < NMAT; ++mm) {
        int remm = nmr[mm] - k0 - NB;
        int w = remm > 0 ? 2 * (remm >> 6) : 0;
        if (job >= bbase && job < bbase + w) { m = mm; local = job - bbase; }
        bbase += w;
      }
      int npt = (nmr[m] - k0 - NB) >> 6;
      int role = (local >= npt) ? 1 : 0;
      int px = role ? local - npt : local;
      __syncthreads();
      panel_job(M, invU, invL, k0, m, role, px, tid, S);
    }
    grid.sync();
    // ---- trail phase (specials are jobs 0..totS-1, start first) ----
    int totS = 0, totR = 0;
#pragma unroll
    for (int mm = 0; mm < NMAT; ++mm) {
      int remm = nmr[mm] - k0 - NB;
      if (remm > 0) {
        int n2 = (remm + 127) >> 7;
        totS += 1;
        totR += n2 * n2 - 1;
      }
    }
    int totB = totS + totR;
    for (int job = bid; job < totB; job += G) {
      int m = 0, ty = 0, tx = 0;
      if (job < totS) {
        int cnt = 0;
#pragma unroll
        for (int mm = 0; mm < NMAT; ++mm) {
          int remm = nmr[mm] - k0 - NB;
          if (remm > 0) { if (cnt == job) m = mm; ++cnt; }
        }
      } else {
        int jr = job - totS, bbase = 0, tloc = 0;
#pragma unroll
        for (int mm = 0; mm < NMAT; ++mm) {
          int remm = nmr[mm] - k0 - NB;
          int n2 = remm > 0 ? (remm + 127) >> 7 : 0;
          int w = n2 > 0 ? n2 * n2 - 1 : 0;
          if (jr >= bbase && jr < bbase + w) { m = mm; tloc = jr - bbase + 1; }
          bbase += w;
        }
        int n2m = (nmr[m] - k0 - NB + 127) >> 7;
        ty = tloc / n2m;
        tx = tloc - ty * n2m;
      }
      int remm = nmr[m] - k0 - NB;
      __syncthreads();
      trail_job(M, invU, invL, k0, remm, m, ty, tx, (remm > 64) ? 1 : 0, tid, S);
    }
    grid.sync();
  }
}

// ---------------- reduction ----------------

__global__ void logdet_kernel(const float* __restrict__ Mb, double* __restrict__ dlog) {
  int m = blockIdx.x;
  const float* A = Mb + (size_t)m * NN * NN;
  double s = 0.0;
  for (int i = threadIdx.x; i < NN; i += 256)
    s += (double)logf(fabsf(A[(size_t)i * NN + i]));
  __shared__ double red[256];
  red[threadIdx.x] = s;
  __syncthreads();
  for (int k = 128; k > 0; k >>= 1) {
    if (threadIdx.x < k) red[threadIdx.x] += red[threadIdx.x + k];
    __syncthreads();
  }
  if (threadIdx.x == 0) dlog[m] = red[0];
}

__global__ void final_kernel(const double* __restrict__ dlog, float* __restrict__ out) {
  if (threadIdx.x == 0) {
    double acc = 0.0;
    for (int b = 0; b < NBATCH; ++b) acc += dlog[b] - dlog[NBATCH + b];
    out[0] = (float)(acc * 0.25);
  }
}

// ---------------- launch ----------------

extern "C" void kernel_launch(void* const* d_in, const int* in_sizes, int n_in,
                              void* d_out, int out_size, void* d_ws, size_t ws_size,
                              hipStream_t stream) {
  const float* scores  = (const float*)d_in[0];
  const float* tm      = (const float*)d_in[1];  // target_mask
  const float* zm      = (const float*)d_in[2];  // z_mask
  const int*   lengths = (const int*)d_in[3];
  float* out = (float*)d_out;

  // ws layout: M (8*2176^2 f32) | cs (8*2176 f32) | dlog (8 f64) | invU | invL
  float* M  = (float*)d_ws;
  float* cs = M + (size_t)NMAT * NN * NN;
  double* dlog = (double*)(cs + (size_t)NMAT * NN);
  float* invU = (float*)(dlog + NMAT);
  float* invL = invU + (size_t)NMAT * 4096;

  // cooperative grid size: co-resident blocks only (cached; host-side queries only)
  static int s_grid = 0;
  if (s_grid == 0) {
    int nb = 0;
    if (hipOccupancyMaxActiveBlocksPerMultiprocessor(&nb, (const void*)lu_coop, 256, 0) != hipSuccess || nb <= 0)
      nb = 3;
    hipDeviceProp_t prop;
    int dev = 0;
    hipGetDevice(&dev);
    int cus = 256;
    if (hipGetDeviceProperties(&prop, dev) == hipSuccess && prop.multiProcessorCount > 0)
      cus = prop.multiProcessorCount;
    s_grid = nb * cus;
    if (s_grid < 64) s_grid = 64;
  }

  const float* s_ = scores; const float* z_ = zm; const float* t_ = tm;
  const int* l_ = lengths;
  float* M_ = M; float* cs_ = cs; float* iU_ = invU; float* iL_ = invL;
  void* kargs[] = {(void*)&s_, (void*)&z_, (void*)&t_, (void*)&l_,
                   (void*)&M_, (void*)&cs_, (void*)&iU_, (void*)&iL_};
  hipLaunchCooperativeKernel((const void*)lu_coop, dim3(s_grid), dim3(256),
                             kargs, 0, stream);

  logdet_kernel<<<NMAT, 256, 0, stream>>>(M, dlog);
  final_kernel<<<1, 64, 0, stream>>>(dlog, out);
}

// Round 7
// 8497.565 us; speedup vs baseline: 1.1753x; 1.1753x over previous
//
#include <hip/hip_runtime.h>
#include <hip/hip_cooperative_groups.h>
#include <math.h>

namespace cg = cooperative_groups;

#define NFULL 2177   // 1 + L + S
#define NN    2176   // minor size (NFULL-1), = 34*64
#define NB    64
#define NMAT  8      // 4 batches x {z, target}
#define NBATCH 4
#define TP    65     // pitch of 64x64 factor/inverse tiles in LDS
#define LTP   132    // Lt quarter pitch (128 rows + pad)
#define UTP   188    // Ut quarter pitch (128 cols + 4-per-8 skew)
#define QL    (16 * LTP)          // 2112 floats
#define QU    (16 * UTP)          // 3008 floats
#define QBUF  (QL + QU)           // 5120 floats per quarter buffer
#define SSZ2  (2 * QBUF)          // 10240 floats = 40 KB

// ---------------- LU building blocks (round-4 verified math, verbatim) ----------------

// Factor 64x64 block in LDS (pitch TP), L unit-lower \ U upper. 256 threads.
__device__ __forceinline__ void factor64(float* T, int tid) {
  int c = tid & 63, g = tid >> 6;
  for (int j = 0; j < 63; ++j) {
    float inv = 1.0f / T[j * TP + j];
    int rs = j + 1 + ((g - j - 1) & 3);
    if (c == j) {
      for (int r = rs; r < 64; r += 4) T[r * TP + j] *= inv;
    }
    __syncthreads();
    if (c > j) {
      float ujc = T[j * TP + c];
      for (int r = rs; r < 64; r += 4) T[r * TP + c] -= T[r * TP + j] * ujc;
    }
    __syncthreads();
  }
}

// Parallel blocked inversion of L (unit-lower) and U from factored T (pitch TP).
__device__ void invert64(const float* T, float* X,
                         float* __restrict__ invUg,
                         float* __restrict__ invLg, int tid) {
  if (tid < 64) {
    int o = (tid >> 5) * 32, jj = tid & 31, j = o + jj;
    X[(o + jj) * TP + j] = 1.0f / T[(o + jj) * TP + (o + jj)];
    for (int i = jj - 1; i >= 0; --i) {
      float s = 0.f;
      for (int t = i + 1; t <= jj; ++t)
        s += T[(o + i) * TP + (o + t)] * X[(o + t) * TP + j];
      X[(o + i) * TP + j] = -s / T[(o + i) * TP + (o + i)];
    }
  }
  __syncthreads();
  for (int e = tid; e < 1024; e += 256) {
    int i = e >> 5, j = e & 31;
    float s = 0.f;
    for (int t = 0; t <= j; ++t)
      s += T[i * TP + 32 + t] * X[(32 + t) * TP + 32 + j];
    X[(32 + i) * TP + j] = s;
  }
  __syncthreads();
  for (int e = tid; e < 1024; e += 256) {
    int i = e >> 5, j = e & 31;
    float s = 0.f;
    for (int t = i; t < 32; ++t)
      s += X[i * TP + t] * X[(32 + t) * TP + j];
    X[i * TP + 32 + j] = -s;
  }
  __syncthreads();
  for (int e = tid; e < 4096; e += 256) {
    int i = e >> 6, j = e & 63;
    float v = 0.f;
    if (i < 32 && j >= 32) v = X[i * TP + j];
    else if ((i >> 5) == (j >> 5) && i <= j) v = X[i * TP + j];
    invUg[e] = v;
  }
  __syncthreads();
  if (tid < 64) {
    int o = (tid >> 5) * 32, jj = tid & 31, j = o + jj;
    X[(o + jj) * TP + j] = 1.0f;
    for (int i = jj + 1; i < 32; ++i) {
      float s = 0.f;
      for (int t = jj; t < i; ++t)
        s += T[(o + i) * TP + (o + t)] * X[(o + t) * TP + j];
      X[(o + i) * TP + j] = -s;
    }
  }
  __syncthreads();
  for (int e = tid; e < 1024; e += 256) {
    int i = e >> 5, j = e & 31;
    float s = 0.f;
    for (int t = j; t < 32; ++t)
      s += T[(32 + i) * TP + t] * X[t * TP + j];
    X[i * TP + 32 + j] = s;
  }
  __syncthreads();
  for (int e = tid; e < 1024; e += 256) {
    int i = e >> 5, j = e & 31;
    float s = 0.f;
    for (int t = 0; t <= i; ++t)
      s += X[(32 + i) * TP + 32 + t] * X[t * TP + 32 + j];
    X[(32 + i) * TP + j] = -s;
  }
  __syncthreads();
  for (int e = tid; e < 4096; e += 256) {
    int i = e >> 6, j = e & 63;
    float v = 0.f;
    if (i >= 32 && j < 32) v = X[i * TP + j];
    else if ((i >> 5) == (j >> 5)) v = (i > j) ? X[i * TP + j] : (i == j ? 1.f : 0.f);
    invLg[e] = v;
  }
}

// Panel tile: role 0 -> L21 = A21 * invU ; role 1 -> U12 = invL * A12
__device__ void panel_job(float* __restrict__ Mb, const float* __restrict__ invUb,
                          const float* __restrict__ invLb, int k0,
                          int m, int role, int px, int tid, float* S) {
  float* Aa = S;            // [64][68], Aa[k][r]
  float* Bb = S + 64 * 68;  // [64][68], Bb[k][c]
  float* A = Mb + (size_t)m * NN * NN;
  int obase = k0 + 64 + px * 64;
  if (role == 0) {
    const float* iU = invUb + (size_t)m * 4096;
    for (int idx = tid; idx < 4096; idx += 256) {
      int r = idx >> 6, k = idx & 63;
      Aa[k * 68 + r] = A[(size_t)(obase + r) * NN + (k0 + k)];
    }
    for (int idx = tid; idx < 4096; idx += 256)
      Bb[(idx >> 6) * 68 + (idx & 63)] = iU[idx];
  } else {
    const float* iL = invLb + (size_t)m * 4096;
    for (int idx = tid; idx < 4096; idx += 256) {
      int r = idx >> 6, k = idx & 63;
      Aa[k * 68 + r] = iL[(r << 6) + k];
    }
    for (int idx = tid; idx < 4096; idx += 256) {
      int k = idx >> 6, c = idx & 63;
      Bb[k * 68 + c] = A[(size_t)(k0 + k) * NN + (obase + c)];
    }
  }
  __syncthreads();
  int c0 = (tid & 15) << 2;
  int r0 = (tid >> 4) << 2;
  float acc[4][4];
#pragma unroll
  for (int i = 0; i < 4; ++i)
#pragma unroll
    for (int jj = 0; jj < 4; ++jj) acc[i][jj] = 0.f;
#pragma unroll 8
  for (int k = 0; k < 64; ++k) {
    float4 a  = *(const float4*)&Aa[k * 68 + r0];
    float4 bv = *(const float4*)&Bb[k * 68 + c0];
    acc[0][0] += a.x * bv.x; acc[0][1] += a.x * bv.y; acc[0][2] += a.x * bv.z; acc[0][3] += a.x * bv.w;
    acc[1][0] += a.y * bv.x; acc[1][1] += a.y * bv.y; acc[1][2] += a.y * bv.z; acc[1][3] += a.y * bv.w;
    acc[2][0] += a.z * bv.x; acc[2][1] += a.z * bv.y; acc[2][2] += a.z * bv.z; acc[2][3] += a.z * bv.w;
    acc[3][0] += a.w * bv.x; acc[3][1] += a.w * bv.y; acc[3][2] += a.w * bv.z; acc[3][3] += a.w * bv.w;
  }
  if (role == 0) {
#pragma unroll
    for (int i = 0; i < 4; ++i) {
      float4 v = make_float4(acc[i][0], acc[i][1], acc[i][2], acc[i][3]);
      *(float4*)&A[(size_t)(obase + r0 + i) * NN + (k0 + c0)] = v;
    }
  } else {
#pragma unroll
    for (int i = 0; i < 4; ++i) {
      float4 v = make_float4(acc[i][0], acc[i][1], acc[i][2], acc[i][3]);
      *(float4*)&A[(size_t)(k0 + r0 + i) * NN + (obase + c0)] = v;
    }
  }
}

// ---- trail staging helpers (reg-staged, software-pipelined) ----

__device__ __forceinline__ void load_quarter_regs(const float* __restrict__ A,
                                                  int rbase, int cbase, int rows, int cols,
                                                  int kb, float* lr, float* ur, int tid) {
#pragma unroll
  for (int s = 0; s < 8; ++s) {
    int idx = tid + s * 256;
    int k = idx & 15, r = idx >> 4;
    int gr = rbase + (r < rows ? r : 0);
    lr[s] = A[(size_t)gr * NN + kb + k];
  }
#pragma unroll
  for (int s = 0; s < 8; ++s) {
    int idx = tid + s * 256;
    int c = idx & 127, k = idx >> 7;
    int gc = cbase + (c < cols ? c : 0);
    ur[s] = A[(size_t)(kb + k) * NN + gc];
  }
}

__device__ __forceinline__ void write_quarter_lds(float* __restrict__ S,
                                                  const float* lr, const float* ur, int tid) {
#pragma unroll
  for (int s = 0; s < 8; ++s) {
    int idx = tid + s * 256;
    int k = idx & 15, r = idx >> 4;
    S[k * LTP + r] = lr[s];
  }
#pragma unroll
  for (int s = 0; s < 8; ++s) {
    int idx = tid + s * 256;
    int c = idx & 127, k = idx >> 7;
    S[QL + k * UTP + c + 4 * (c >> 3)] = ur[s];
  }
}

// Trailing-update tile 128x128: A22 -= L21*U12. 8x8 micro, K=64 in four
// pipelined quarters. Special tile (0,0): also factor next diag + inverses.
__device__ void trail_job(float* __restrict__ Mb, float* __restrict__ invUb,
                          float* __restrict__ invLb, int k0, int remm,
                          int m, int tyt, int txt, int do_inv, int tid, float* S) {
  float* A = Mb + (size_t)m * NN * NN;
  int base = k0 + NB;
  int rbase = base + tyt * 128, cbase = base + txt * 128;
  int rows = remm - tyt * 128; if (rows > 128) rows = 128;
  int cols = remm - txt * 128; if (cols > 128) cols = 128;
  int tx = tid & 15, ty = tid >> 4;
  int rr = ty * 8, cc = tx * 8;
  int ccs = 12 * tx;            // skewed Ut offset: cc + 4*(cc>>3)
  float acc[8][8];
#pragma unroll
  for (int i = 0; i < 8; ++i)
#pragma unroll
    for (int j = 0; j < 8; ++j) acc[i][j] = 0.f;

  float lr[8], ur[8];
  load_quarter_regs(A, rbase, cbase, rows, cols, k0, lr, ur, tid);
  write_quarter_lds(S, lr, ur, tid);
  __syncthreads();

#pragma unroll
  for (int q = 0; q < 4; ++q) {
    if (q < 3)
      load_quarter_regs(A, rbase, cbase, rows, cols, k0 + (q + 1) * 16, lr, ur, tid);
    const float* Sc = S + (q & 1) * QBUF;
#pragma unroll
    for (int k = 0; k < 16; ++k) {
      const float* lp = &Sc[k * LTP + rr];
      const float* up = &Sc[QL + k * UTP + ccs];
      float4 a0 = *(const float4*)lp;
      float4 a1 = *(const float4*)(lp + 4);
      float4 b0 = *(const float4*)up;
      float4 b1 = *(const float4*)(up + 4);
      acc[0][0] += a0.x * b0.x; acc[0][1] += a0.x * b0.y; acc[0][2] += a0.x * b0.z; acc[0][3] += a0.x * b0.w;
      acc[0][4] += a0.x * b1.x; acc[0][5] += a0.x * b1.y; acc[0][6] += a0.x * b1.z; acc[0][7] += a0.x * b1.w;
      acc[1][0] += a0.y * b0.x; acc[1][1] += a0.y * b0.y; acc[1][2] += a0.y * b0.z; acc[1][3] += a0.y * b0.w;
      acc[1][4] += a0.y * b1.x; acc[1][5] += a0.y * b1.y; acc[1][6] += a0.y * b1.z; acc[1][7] += a0.y * b1.w;
      acc[2][0] += a0.z * b0.x; acc[2][1] += a0.z * b0.y; acc[2][2] += a0.z * b0.z; acc[2][3] += a0.z * b0.w;
      acc[2][4] += a0.z * b1.x; acc[2][5] += a0.z * b1.y; acc[2][6] += a0.z * b1.z; acc[2][7] += a0.z * b1.w;
      acc[3][0] += a0.w * b0.x; acc[3][1] += a0.w * b0.y; acc[3][2] += a0.w * b0.z; acc[3][3] += a0.w * b0.w;
      acc[3][4] += a0.w * b1.x; acc[3][5] += a0.w * b1.y; acc[3][6] += a0.w * b1.z; acc[3][7] += a0.w * b1.w;
      acc[4][0] += a1.x * b0.x; acc[4][1] += a1.x * b0.y; acc[4][2] += a1.x * b0.z; acc[4][3] += a1.x * b0.w;
      acc[4][4] += a1.x * b1.x; acc[4][5] += a1.x * b1.y; acc[4][6] += a1.x * b1.z; acc[4][7] += a1.x * b1.w;
      acc[5][0] += a1.y * b0.x; acc[5][1] += a1.y * b0.y; acc[5][2] += a1.y * b0.z; acc[5][3] += a1.y * b0.w;
      acc[5][4] += a1.y * b1.x; acc[5][5] += a1.y * b1.y; acc[5][6] += a1.y * b1.z; acc[5][7] += a1.y * b1.w;
      acc[6][0] += a1.z * b0.x; acc[6][1] += a1.z * b0.y; acc[6][2] += a1.z * b0.z; acc[6][3] += a1.z * b0.w;
      acc[6][4] += a1.z * b1.x; acc[6][5] += a1.z * b1.y; acc[6][6] += a1.z * b1.z; acc[6][7] += a1.z * b1.w;
      acc[7][0] += a1.w * b0.x; acc[7][1] += a1.w * b0.y; acc[7][2] += a1.w * b0.z; acc[7][3] += a1.w * b0.w;
      acc[7][4] += a1.w * b1.x; acc[7][5] += a1.w * b1.y; acc[7][6] += a1.w * b1.z; acc[7][7] += a1.w * b1.w;
    }
    __syncthreads();
    if (q < 3) {
      write_quarter_lds(S + ((q + 1) & 1) * QBUF, lr, ur, tid);
      __syncthreads();
    }
  }

  bool special = (txt == 0 && tyt == 0);
  if (!special) {
    if (cc < cols) {
#pragma unroll
      for (int i = 0; i < 8; ++i) {
        int r = rr + i;
        if (r < rows) {
          float4* p = (float4*)&A[(size_t)(rbase + r) * NN + cbase + cc];
          float4 v0 = p[0], v1 = p[1];
          v0.x -= acc[i][0]; v0.y -= acc[i][1]; v0.z -= acc[i][2]; v0.w -= acc[i][3];
          v1.x -= acc[i][4]; v1.y -= acc[i][5]; v1.z -= acc[i][6]; v1.w -= acc[i][7];
          p[0] = v0; p[1] = v1;
        }
      }
    }
    return;
  }
  // special: top-left 64x64 quadrant IS the next diagonal block
  float* T = S;            // 64x64, pitch TP
  float* X = S + 4224;     // 64x64, pitch TP
  if (cc < cols) {
#pragma unroll
    for (int i = 0; i < 8; ++i) {
      int r = rr + i;
      if (r < rows) {
        float4* p = (float4*)&A[(size_t)(rbase + r) * NN + cbase + cc];
        float4 v0 = p[0], v1 = p[1];
        v0.x -= acc[i][0]; v0.y -= acc[i][1]; v0.z -= acc[i][2]; v0.w -= acc[i][3];
        v1.x -= acc[i][4]; v1.y -= acc[i][5]; v1.z -= acc[i][6]; v1.w -= acc[i][7];
        if (r < 64 && cc < 64) {
          float* t = &T[r * TP + cc];
          t[0] = v0.x; t[1] = v0.y; t[2] = v0.z; t[3] = v0.w;
          t[4] = v1.x; t[5] = v1.y; t[6] = v1.z; t[7] = v1.w;
        } else {
          p[0] = v0; p[1] = v1;
        }
      }
    }
  }
  __syncthreads();
  factor64(T, tid);
  for (int idx = tid; idx < 4096; idx += 256) {
    int r = idx >> 6, c = idx & 63;
    A[(size_t)(base + r) * NN + base + c] = T[r * TP + c];
  }
  if (do_inv)
    invert64(T, X, invUb + (size_t)m * 4096, invLb + (size_t)m * 4096, tid);
}

// ---------------- the persistent cooperative kernel ----------------

__global__ __launch_bounds__(256, 2) void lu_coop(const float* __restrict__ scores,
                                                  const float* __restrict__ zm,
                                                  const float* __restrict__ tm,
                                                  const int* __restrict__ lengths,
                                                  float* __restrict__ M,
                                                  float* __restrict__ cs,
                                                  float* __restrict__ invU,
                                                  float* __restrict__ invL) {
  __shared__ float S[SSZ2];
  cg::grid_group grid = cg::this_grid();
  const int tid = threadIdx.x;
  const int bid = blockIdx.x;
  const int G = gridDim.x;

  // per-matrix active minor size, rounded up to 64 (pad region stays identity)
  int nmr[NMAT];
#pragma unroll
  for (int mm = 0; mm < NMAT; ++mm) {
    int nm = lengths[mm & 3] - 1;
    nm = (nm + 63) & ~63;
    if (nm < 64) nm = 64;
    if (nm > NN) nm = NN;
    nmr[mm] = nm;
  }

  // phase 0: zero column sums
  for (int i = bid * 256 + tid; i < NMAT * NN; i += G * 256) cs[i] = 0.f;
  grid.sync();

  // phase 1: build off-diagonals + column sums (single pass over inputs)
  for (int job = bid; job < 9 * 34 * NBATCH; job += G) {
    int b = job / (9 * 34);
    int rj = job - b * (9 * 34);
    int ry = rj / 9, cx = rj - ry * 9;
    int c = cx * 256 + tid;
    if (c < NN) {
      int len = lengths[b];
      int j = c + 1;
      bool jv = (j < len);
      int r0 = ry * 64;
      size_t sbase = (size_t)b * NFULL * NFULL + j;
      float az = 0.f, at = 0.f;
      if (ry == 0 && jv) {
        float e = __expf(scores[sbase]);
        az += e * zm[sbase];
        at += e * tm[sbase];
      }
      size_t mz = (size_t)b * NN * NN + (size_t)r0 * NN + c;
      size_t mt = (size_t)(NBATCH + b) * NN * NN + (size_t)r0 * NN + c;
      for (int rrr = 0; rrr < 64; ++rrr) {
        int i = r0 + rrr + 1;
        float vz = 0.f, vt = 0.f;
        if (jv && i < len) {
          size_t off = sbase + (size_t)i * NFULL;
          float e = __expf(scores[off]);
          vz = e * zm[off];
          vt = e * tm[off];
          az += vz;
          at += vt;
        }
        M[mz] = -vz;
        M[mt] = -vt;
        mz += NN;
        mt += NN;
      }
      if (az != 0.f) atomicAdd(&cs[b * NN + c], az);
      if (at != 0.f) atomicAdd(&cs[(NBATCH + b) * NN + c], at);
    }
  }
  grid.sync();

  // phase 2: diagonal = colsum + pad
  for (int i = bid * 256 + tid; i < NMAT * NN; i += G * 256) {
    int mm = i / NN, c = i - mm * NN;
    int len = lengths[mm & 3];
    float pad = (c + 1 < len) ? 0.f : 1.f;
    M[(size_t)mm * NN * NN + (size_t)c * NN + c] = cs[i] + pad;
  }
  grid.sync();

  // phase 3: factor + invert diagonal block 0
  if (bid < NMAT) {
    float* A = M + (size_t)bid * NN * NN;
    for (int idx = tid; idx < 4096; idx += 256)
      S[(idx >> 6) * TP + (idx & 63)] = A[(size_t)(idx >> 6) * NN + (idx & 63)];
    __syncthreads();
    factor64(S, tid);
    for (int idx = tid; idx < 4096; idx += 256)
      A[(size_t)(idx >> 6) * NN + (idx & 63)] = S[(idx >> 6) * TP + (idx & 63)];
    invert64(S, S + 4224, invU + (size_t)bid * 4096, invL + (size_t)bid * 4096, tid);
  }
  grid.sync();

  // LU loop: 33 iterations, 2 grid syncs each
  for (int k0 = 0; k0 + NB < NN; k0 += NB) {
    // ---- panel phase ----
    int totA = 0;
#pragma unroll
    for (int mm = 0; mm < NMAT; ++mm) {
      int remm = nmr[mm] - k0 - NB;
      if (remm > 0) totA += 2 * (remm >> 6);
    }
    for (int job = bid; job < totA; job += G) {
      int m = 0, local = 0, bbase = 0;
#pragma unroll
      for (int mm = 0; mm < NMAT; ++mm) {
        int remm = nmr[mm] - k0 - NB;
        int w = remm > 0 ? 2 * (remm >> 6) : 0;
        if (job >= bbase && job < bbase + w) { m = mm; local = job - bbase; }
        bbase += w;
      }
      int npt = (nmr[m] - k0 - NB) >> 6;
      int role = (local >= npt) ? 1 : 0;
      int px = role ? local - npt : local;
      __syncthreads();
      panel_job(M, invU, invL, k0, m, role, px, tid, S);
    }
    grid.sync();
    // ---- trail phase (specials are jobs 0..totS-1, start first) ----
    int totS = 0, totR = 0;
#pragma unroll
    for (int mm = 0; mm < NMAT; ++mm) {
      int remm = nmr[mm] - k0 - NB;
      if (remm > 0) {
        int n2 = (remm + 127) >> 7;
        totS += 1;
        totR += n2 * n2 - 1;
      }
    }
    int totB = totS + totR;
    for (int job = bid; job < totB; job += G) {
      int m = 0, ty = 0, tx = 0;
      if (job < totS) {
        int cnt = 0;
#pragma unroll
        for (int mm = 0; mm < NMAT; ++mm) {
          int remm = nmr[mm] - k0 - NB;
          if (remm > 0) { if (cnt == job) m = mm; ++cnt; }
        }
      } else {
        int jr = job - totS, bbase = 0, tloc = 0;
#pragma unroll
        for (int mm = 0; mm < NMAT; ++mm) {
          int remm = nmr[mm] - k0 - NB;
          int n2 = remm > 0 ? (remm + 127) >> 7 : 0;
          int w = n2 > 0 ? n2 * n2 - 1 : 0;
          if (jr >= bbase && jr < bbase + w) { m = mm; tloc = jr - bbase + 1; }
          bbase += w;
        }
        int n2m = (nmr[m] - k0 - NB + 127) >> 7;
        ty = tloc / n2m;
        tx = tloc - ty * n2m;
      }
      int remm = nmr[m] - k0 - NB;
      __syncthreads();
      trail_job(M, invU, invL, k0, remm, m, ty, tx, (remm > 64) ? 1 : 0, tid, S);
    }
    grid.sync();
  }
}

// ---------------- reduction ----------------

__global__ void logdet_kernel(const float* __restrict__ Mb, double* __restrict__ dlog) {
  int m = blockIdx.x;
  const float* A = Mb + (size_t)m * NN * NN;
  double s = 0.0;
  for (int i = threadIdx.x; i < NN; i += 256)
    s += (double)logf(fabsf(A[(size_t)i * NN + i]));
  __shared__ double red[256];
  red[threadIdx.x] = s;
  __syncthreads();
  for (int k = 128; k > 0; k >>= 1) {
    if (threadIdx.x < k) red[threadIdx.x] += red[threadIdx.x + k];
    __syncthreads();
  }
  if (threadIdx.x == 0) dlog[m] = red[0];
}

__global__ void final_kernel(const double* __restrict__ dlog, float* __restrict__ out) {
  if (threadIdx.x == 0) {
    double acc = 0.0;
    for (int b = 0; b < NBATCH; ++b) acc += dlog[b] - dlog[NBATCH + b];
    out[0] = (float)(acc * 0.25);
  }
}

// ---------------- launch ----------------

extern "C" void kernel_launch(void* const* d_in, const int* in_sizes, int n_in,
                              void* d_out, int out_size, void* d_ws, size_t ws_size,
                              hipStream_t stream) {
  const float* scores  = (const float*)d_in[0];
  const float* tm      = (const float*)d_in[1];  // target_mask
  const float* zm      = (const float*)d_in[2];  // z_mask
  const int*   lengths = (const int*)d_in[3];
  float* out = (float*)d_out;

  // ws layout: M (8*2176^2 f32) | cs (8*2176 f32) | dlog (8 f64) | invU | invL
  float* M  = (float*)d_ws;
  float* cs = M + (size_t)NMAT * NN * NN;
  double* dlog = (double*)(cs + (size_t)NMAT * NN);
  float* invU = (float*)(dlog + NMAT);
  float* invL = invU + (size_t)NMAT * 4096;

  // cooperative grid size: co-resident blocks only (cached; host-side queries only)
  static int s_grid = 0;
  if (s_grid == 0) {
    int nb = 0;
    if (hipOccupancyMaxActiveBlocksPerMultiprocessor(&nb, (const void*)lu_coop, 256, 0) != hipSuccess || nb <= 0)
      nb = 2;
    if (nb > 4) nb = 4;
    hipDeviceProp_t prop;
    int dev = 0;
    hipGetDevice(&dev);
    int cus = 256;
    if (hipGetDeviceProperties(&prop, dev) == hipSuccess && prop.multiProcessorCount > 0)
      cus = prop.multiProcessorCount;
    s_grid = nb * cus;
    if (s_grid < 256) s_grid = 256;
  }

  const float* s_ = scores; const float* z_ = zm; const float* t_ = tm;
  const int* l_ = lengths;
  float* M_ = M; float* cs_ = cs; float* iU_ = invU; float* iL_ = invL;
  void* kargs[] = {(void*)&s_, (void*)&z_, (void*)&t_, (void*)&l_,
                   (void*)&M_, (void*)&cs_, (void*)&iU_, (void*)&iL_};

  // Launch with fallback ladder: a silent capacity failure must never again
  // masquerade as a numerics bug (rounds 5/6 post-mortem).
  hipError_t e = hipLaunchCooperativeKernel((const void*)lu_coop, dim3(s_grid),
                                            dim3(256), kargs, 0, stream);
  if (e != hipSuccess && s_grid > 512) {
    e = hipLaunchCooperativeKernel((const void*)lu_coop, dim3(512),
                                   dim3(256), kargs, 0, stream);
    if (e == hipSuccess) s_grid = 512;
  }
  if (e != hipSuccess) {
    e = hipLaunchCooperativeKernel((const void*)lu_coop, dim3(256),
                                   dim3(256), kargs, 0, stream);
    if (e == hipSuccess) s_grid = 256;
  }

  logdet_kernel<<<NMAT, 256, 0, stream>>>(M, dlog);
  final_kernel<<<1, 64, 0, stream>>>(dlog, out);
}

// Round 8
// 7321.110 us; speedup vs baseline: 1.3642x; 1.1607x over previous
//
#include <hip/hip_runtime.h>
#include <math.h>

#define NFULL 2177   // 1 + L + S
#define NN    2176   // minor size (NFULL-1), = 34*64
#define NB    64
#define NMAT  8      // 4 batches x {z, target}
#define NBATCH 4
#define TP    65     // pitch of 64x64 factor/inverse tiles in LDS
#define LTP   132    // Lt quarter pitch (128 rows + pad)
#define UTP   188    // Ut quarter pitch (128 cols + 4-per-8 skew)
#define QL    (16 * LTP)          // 2112 floats
#define QU    (16 * UTP)          // 3008 floats
#define QBUF  (QL + QU)           // 5120 floats per quarter buffer
#define SSZ2  (2 * QBUF)          // 10240 floats = 40 KB
#define NCH   34                  // flag slots per matrix (64-chunks, 33 used)
#define NIT   34                  // queue counters (33 used)

// ---------------- LU building blocks (round-7 verified math, verbatim) ----------------

__device__ __forceinline__ void factor64(float* T, int tid) {
  int c = tid & 63, g = tid >> 6;
  for (int j = 0; j < 63; ++j) {
    float inv = 1.0f / T[j * TP + j];
    int rs = j + 1 + ((g - j - 1) & 3);
    if (c == j) {
      for (int r = rs; r < 64; r += 4) T[r * TP + j] *= inv;
    }
    __syncthreads();
    if (c > j) {
      float ujc = T[j * TP + c];
      for (int r = rs; r < 64; r += 4) T[r * TP + c] -= T[r * TP + j] * ujc;
    }
    __syncthreads();
  }
}

__device__ void invert64(const float* T, float* X,
                         float* __restrict__ invUg,
                         float* __restrict__ invLg, int tid) {
  if (tid < 64) {
    int o = (tid >> 5) * 32, jj = tid & 31, j = o + jj;
    X[(o + jj) * TP + j] = 1.0f / T[(o + jj) * TP + (o + jj)];
    for (int i = jj - 1; i >= 0; --i) {
      float s = 0.f;
      for (int t = i + 1; t <= jj; ++t)
        s += T[(o + i) * TP + (o + t)] * X[(o + t) * TP + j];
      X[(o + i) * TP + j] = -s / T[(o + i) * TP + (o + i)];
    }
  }
  __syncthreads();
  for (int e = tid; e < 1024; e += 256) {
    int i = e >> 5, j = e & 31;
    float s = 0.f;
    for (int t = 0; t <= j; ++t)
      s += T[i * TP + 32 + t] * X[(32 + t) * TP + 32 + j];
    X[(32 + i) * TP + j] = s;
  }
  __syncthreads();
  for (int e = tid; e < 1024; e += 256) {
    int i = e >> 5, j = e & 31;
    float s = 0.f;
    for (int t = i; t < 32; ++t)
      s += X[i * TP + t] * X[(32 + t) * TP + j];
    X[i * TP + 32 + j] = -s;
  }
  __syncthreads();
  for (int e = tid; e < 4096; e += 256) {
    int i = e >> 6, j = e & 63;
    float v = 0.f;
    if (i < 32 && j >= 32) v = X[i * TP + j];
    else if ((i >> 5) == (j >> 5) && i <= j) v = X[i * TP + j];
    invUg[e] = v;
  }
  __syncthreads();
  if (tid < 64) {
    int o = (tid >> 5) * 32, jj = tid & 31, j = o + jj;
    X[(o + jj) * TP + j] = 1.0f;
    for (int i = jj + 1; i < 32; ++i) {
      float s = 0.f;
      for (int t = jj; t < i; ++t)
        s += T[(o + i) * TP + (o + t)] * X[(o + t) * TP + j];
      X[(o + i) * TP + j] = -s;
    }
  }
  __syncthreads();
  for (int e = tid; e < 1024; e += 256) {
    int i = e >> 5, j = e & 31;
    float s = 0.f;
    for (int t = j; t < 32; ++t)
      s += T[(32 + i) * TP + t] * X[t * TP + j];
    X[i * TP + 32 + j] = s;
  }
  __syncthreads();
  for (int e = tid; e < 1024; e += 256) {
    int i = e >> 5, j = e & 31;
    float s = 0.f;
    for (int t = 0; t <= i; ++t)
      s += X[(32 + i) * TP + 32 + t] * X[t * TP + 32 + j];
    X[(32 + i) * TP + j] = -s;
  }
  __syncthreads();
  for (int e = tid; e < 4096; e += 256) {
    int i = e >> 6, j = e & 63;
    float v = 0.f;
    if (i >= 32 && j < 32) v = X[i * TP + j];
    else if ((i >> 5) == (j >> 5)) v = (i > j) ? X[i * TP + j] : (i == j ? 1.f : 0.f);
    invLg[e] = v;
  }
}

// Panel tile: role 0 -> L21 = A21 * invU ; role 1 -> U12 = invL * A12
__device__ void panel_job(float* __restrict__ Mb, const float* __restrict__ invUb,
                          const float* __restrict__ invLb, int k0,
                          int m, int role, int px, int tid, float* S) {
  float* Aa = S;            // [64][68], Aa[k][r]
  float* Bb = S + 64 * 68;  // [64][68], Bb[k][c]
  float* A = Mb + (size_t)m * NN * NN;
  int obase = k0 + 64 + px * 64;
  if (role == 0) {
    const float* iU = invUb + (size_t)m * 4096;
    for (int idx = tid; idx < 4096; idx += 256) {
      int r = idx >> 6, k = idx & 63;
      Aa[k * 68 + r] = A[(size_t)(obase + r) * NN + (k0 + k)];
    }
    for (int idx = tid; idx < 4096; idx += 256)
      Bb[(idx >> 6) * 68 + (idx & 63)] = iU[idx];
  } else {
    const float* iL = invLb + (size_t)m * 4096;
    for (int idx = tid; idx < 4096; idx += 256) {
      int r = idx >> 6, k = idx & 63;
      Aa[k * 68 + r] = iL[(r << 6) + k];
    }
    for (int idx = tid; idx < 4096; idx += 256) {
      int k = idx >> 6, c = idx & 63;
      Bb[k * 68 + c] = A[(size_t)(k0 + k) * NN + (obase + c)];
    }
  }
  __syncthreads();
  int c0 = (tid & 15) << 2;
  int r0 = (tid >> 4) << 2;
  float acc[4][4];
#pragma unroll
  for (int i = 0; i < 4; ++i)
#pragma unroll
    for (int jj = 0; jj < 4; ++jj) acc[i][jj] = 0.f;
#pragma unroll 8
  for (int k = 0; k < 64; ++k) {
    float4 a  = *(const float4*)&Aa[k * 68 + r0];
    float4 bv = *(const float4*)&Bb[k * 68 + c0];
    acc[0][0] += a.x * bv.x; acc[0][1] += a.x * bv.y; acc[0][2] += a.x * bv.z; acc[0][3] += a.x * bv.w;
    acc[1][0] += a.y * bv.x; acc[1][1] += a.y * bv.y; acc[1][2] += a.y * bv.z; acc[1][3] += a.y * bv.w;
    acc[2][0] += a.z * bv.x; acc[2][1] += a.z * bv.y; acc[2][2] += a.z * bv.z; acc[2][3] += a.z * bv.w;
    acc[3][0] += a.w * bv.x; acc[3][1] += a.w * bv.y; acc[3][2] += a.w * bv.z; acc[3][3] += a.w * bv.w;
  }
  if (role == 0) {
#pragma unroll
    for (int i = 0; i < 4; ++i) {
      float4 v = make_float4(acc[i][0], acc[i][1], acc[i][2], acc[i][3]);
      *(float4*)&A[(size_t)(obase + r0 + i) * NN + (k0 + c0)] = v;
    }
  } else {
#pragma unroll
    for (int i = 0; i < 4; ++i) {
      float4 v = make_float4(acc[i][0], acc[i][1], acc[i][2], acc[i][3]);
      *(float4*)&A[(size_t)(k0 + r0 + i) * NN + (obase + c0)] = v;
    }
  }
}

// ---- trail staging helpers (reg-staged, software-pipelined) ----

__device__ __forceinline__ void load_quarter_regs(const float* __restrict__ A,
                                                  int rbase, int cbase, int rows, int cols,
                                                  int kb, float* lr, float* ur, int tid) {
#pragma unroll
  for (int s = 0; s < 8; ++s) {
    int idx = tid + s * 256;
    int k = idx & 15, r = idx >> 4;
    int gr = rbase + (r < rows ? r : 0);
    lr[s] = A[(size_t)gr * NN + kb + k];
  }
#pragma unroll
  for (int s = 0; s < 8; ++s) {
    int idx = tid + s * 256;
    int c = idx & 127, k = idx >> 7;
    int gc = cbase + (c < cols ? c : 0);
    ur[s] = A[(size_t)(kb + k) * NN + gc];
  }
}

__device__ __forceinline__ void write_quarter_lds(float* __restrict__ S,
                                                  const float* lr, const float* ur, int tid) {
#pragma unroll
  for (int s = 0; s < 8; ++s) {
    int idx = tid + s * 256;
    int k = idx & 15, r = idx >> 4;
    S[k * LTP + r] = lr[s];
  }
#pragma unroll
  for (int s = 0; s < 8; ++s) {
    int idx = tid + s * 256;
    int c = idx & 127, k = idx >> 7;
    S[QL + k * UTP + c + 4 * (c >> 3)] = ur[s];
  }
}

// Trailing-update tile 128x128: A22 -= L21*U12. Special tile (0,0): also
// factor next diag + inverses. (round-7 verified, verbatim)
__device__ void trail_job(float* __restrict__ Mb, float* __restrict__ invUb,
                          float* __restrict__ invLb, int k0, int remm,
                          int m, int tyt, int txt, int do_inv, int tid, float* S) {
  float* A = Mb + (size_t)m * NN * NN;
  int base = k0 + NB;
  int rbase = base + tyt * 128, cbase = base + txt * 128;
  int rows = remm - tyt * 128; if (rows > 128) rows = 128;
  int cols = remm - txt * 128; if (cols > 128) cols = 128;
  int tx = tid & 15, ty = tid >> 4;
  int rr = ty * 8, cc = tx * 8;
  int ccs = 12 * tx;            // skewed Ut offset: cc + 4*(cc>>3)
  float acc[8][8];
#pragma unroll
  for (int i = 0; i < 8; ++i)
#pragma unroll
    for (int j = 0; j < 8; ++j) acc[i][j] = 0.f;

  float lr[8], ur[8];
  load_quarter_regs(A, rbase, cbase, rows, cols, k0, lr, ur, tid);
  write_quarter_lds(S, lr, ur, tid);
  __syncthreads();

#pragma unroll
  for (int q = 0; q < 4; ++q) {
    if (q < 3)
      load_quarter_regs(A, rbase, cbase, rows, cols, k0 + (q + 1) * 16, lr, ur, tid);
    const float* Sc = S + (q & 1) * QBUF;
#pragma unroll
    for (int k = 0; k < 16; ++k) {
      const float* lp = &Sc[k * LTP + rr];
      const float* up = &Sc[QL + k * UTP + ccs];
      float4 a0 = *(const float4*)lp;
      float4 a1 = *(const float4*)(lp + 4);
      float4 b0 = *(const float4*)up;
      float4 b1 = *(const float4*)(up + 4);
      acc[0][0] += a0.x * b0.x; acc[0][1] += a0.x * b0.y; acc[0][2] += a0.x * b0.z; acc[0][3] += a0.x * b0.w;
      acc[0][4] += a0.x * b1.x; acc[0][5] += a0.x * b1.y; acc[0][6] += a0.x * b1.z; acc[0][7] += a0.x * b1.w;
      acc[1][0] += a0.y * b0.x; acc[1][1] += a0.y * b0.y; acc[1][2] += a0.y * b0.z; acc[1][3] += a0.y * b0.w;
      acc[1][4] += a0.y * b1.x; acc[1][5] += a0.y * b1.y; acc[1][6] += a0.y * b1.z; acc[1][7] += a0.y * b1.w;
      acc[2][0] += a0.z * b0.x; acc[2][1] += a0.z * b0.y; acc[2][2] += a0.z * b0.z; acc[2][3] += a0.z * b0.w;
      acc[2][4] += a0.z * b1.x; acc[2][5] += a0.z * b1.y; acc[2][6] += a0.z * b1.z; acc[2][7] += a0.z * b1.w;
      acc[3][0] += a0.w * b0.x; acc[3][1] += a0.w * b0.y; acc[3][2] += a0.w * b0.z; acc[3][3] += a0.w * b0.w;
      acc[3][4] += a0.w * b1.x; acc[3][5] += a0.w * b1.y; acc[3][6] += a0.w * b1.z; acc[3][7] += a0.w * b1.w;
      acc[4][0] += a1.x * b0.x; acc[4][1] += a1.x * b0.y; acc[4][2] += a1.x * b0.z; acc[4][3] += a1.x * b0.w;
      acc[4][4] += a1.x * b1.x; acc[4][5] += a1.x * b1.y; acc[4][6] += a1.x * b1.z; acc[4][7] += a1.x * b1.w;
      acc[5][0] += a1.y * b0.x; acc[5][1] += a1.y * b0.y; acc[5][2] += a1.y * b0.z; acc[5][3] += a1.y * b0.w;
      acc[5][4] += a1.y * b1.x; acc[5][5] += a1.y * b1.y; acc[5][6] += a1.y * b1.z; acc[5][7] += a1.y * b1.w;
      acc[6][0] += a1.z * b0.x; acc[6][1] += a1.z * b0.y; acc[6][2] += a1.z * b0.z; acc[6][3] += a1.z * b0.w;
      acc[6][4] += a1.z * b1.x; acc[6][5] += a1.z * b1.y; acc[6][6] += a1.z * b1.z; acc[6][7] += a1.z * b1.w;
      acc[7][0] += a1.w * b0.x; acc[7][1] += a1.w * b0.y; acc[7][2] += a1.w * b0.z; acc[7][3] += a1.w * b0.w;
      acc[7][4] += a1.w * b1.x; acc[7][5] += a1.w * b1.y; acc[7][6] += a1.w * b1.z; acc[7][7] += a1.w * b1.w;
    }
    __syncthreads();
    if (q < 3) {
      write_quarter_lds(S + ((q + 1) & 1) * QBUF, lr, ur, tid);
      __syncthreads();
    }
  }

  bool special = (txt == 0 && tyt == 0);
  if (!special) {
    if (cc < cols) {
#pragma unroll
      for (int i = 0; i < 8; ++i) {
        int r = rr + i;
        if (r < rows) {
          float4* p = (float4*)&A[(size_t)(rbase + r) * NN + cbase + cc];
          float4 v0 = p[0], v1 = p[1];
          v0.x -= acc[i][0]; v0.y -= acc[i][1]; v0.z -= acc[i][2]; v0.w -= acc[i][3];
          v1.x -= acc[i][4]; v1.y -= acc[i][5]; v1.z -= acc[i][6]; v1.w -= acc[i][7];
          p[0] = v0; p[1] = v1;
        }
      }
    }
    return;
  }
  float* T = S;            // 64x64, pitch TP
  float* X = S + 4224;     // 64x64, pitch TP
  if (cc < cols) {
#pragma unroll
    for (int i = 0; i < 8; ++i) {
      int r = rr + i;
      if (r < rows) {
        float4* p = (float4*)&A[(size_t)(rbase + r) * NN + cbase + cc];
        float4 v0 = p[0], v1 = p[1];
        v0.x -= acc[i][0]; v0.y -= acc[i][1]; v0.z -= acc[i][2]; v0.w -= acc[i][3];
        v1.x -= acc[i][4]; v1.y -= acc[i][5]; v1.z -= acc[i][6]; v1.w -= acc[i][7];
        if (r < 64 && cc < 64) {
          float* t = &T[r * TP + cc];
          t[0] = v0.x; t[1] = v0.y; t[2] = v0.z; t[3] = v0.w;
          t[4] = v1.x; t[5] = v1.y; t[6] = v1.z; t[7] = v1.w;
        } else {
          p[0] = v0; p[1] = v1;
        }
      }
    }
  }
  __syncthreads();
  factor64(T, tid);
  for (int idx = tid; idx < 4096; idx += 256) {
    int r = idx >> 6, c = idx & 63;
    A[(size_t)(base + r) * NN + base + c] = T[r * TP + c];
  }
  if (do_inv)
    invert64(T, X, invUb + (size_t)m * 4096, invLb + (size_t)m * 4096, tid);
}

// ---------------- build phase (round-3 verified kernels) ----------------

__global__ void init_all(float* __restrict__ cs, int* __restrict__ qctr,
                         int* __restrict__ Lf, int* __restrict__ Uf) {
  int i = blockIdx.x * blockDim.x + threadIdx.x;
  if (i < NMAT * NN) cs[i] = 0.f;
  if (i < NIT) qctr[i] = 0;
  if (i < NMAT * NCH) { Lf[i] = 0; Uf[i] = 0; }
}

__global__ __launch_bounds__(256) void build_fused(const float* __restrict__ scores,
                                                   const float* __restrict__ zm,
                                                   const float* __restrict__ tm,
                                                   const int* __restrict__ lengths,
                                                   float* __restrict__ cs,
                                                   float* __restrict__ M) {
  int c = blockIdx.x * 256 + threadIdx.x;
  if (c >= NN) return;
  int b = blockIdx.z;
  int len = lengths[b];
  int j = c + 1;
  bool jv = (j < len);
  int r0 = blockIdx.y * 64;
  size_t sbase = (size_t)b * NFULL * NFULL + j;
  float az = 0.f, at = 0.f;
  if (blockIdx.y == 0 && jv) {
    float e = __expf(scores[sbase]);
    az += e * zm[sbase];
    at += e * tm[sbase];
  }
  size_t mz = (size_t)b * NN * NN + (size_t)r0 * NN + c;
  size_t mt = (size_t)(NBATCH + b) * NN * NN + (size_t)r0 * NN + c;
  for (int rr = 0; rr < 64; ++rr) {
    int i = r0 + rr + 1;
    float vz = 0.f, vt = 0.f;
    if (jv && i < len) {
      size_t off = sbase + (size_t)i * NFULL;
      float e = __expf(scores[off]);
      vz = e * zm[off];
      vt = e * tm[off];
      az += vz;
      at += vt;
    }
    M[mz] = -vz;
    M[mt] = -vt;
    mz += NN;
    mt += NN;
  }
  if (az != 0.f) atomicAdd(&cs[b * NN + c], az);
  if (at != 0.f) atomicAdd(&cs[(NBATCH + b) * NN + c], at);
}

__global__ void diag_fix(const int* __restrict__ lengths,
                         const float* __restrict__ cs,
                         float* __restrict__ M) {
  int idx = blockIdx.x * 256 + threadIdx.x;
  if (idx >= NMAT * NN) return;
  int mm = idx / NN, c = idx - mm * NN;
  int len = lengths[mm & 3];
  float pad = (c + 1 < len) ? 0.f : 1.f;
  M[(size_t)mm * NN * NN + (size_t)c * NN + c] = cs[idx] + pad;
}

__global__ __launch_bounds__(256) void factor0(float* __restrict__ Mb,
                                               float* __restrict__ invUb,
                                               float* __restrict__ invLb) {
  __shared__ float T[64 * TP];
  __shared__ float X[64 * TP];
  int m = blockIdx.x, tid = threadIdx.x;
  float* A = Mb + (size_t)m * NN * NN;
  for (int idx = tid; idx < 4096; idx += 256)
    T[(idx >> 6) * TP + (idx & 63)] = A[(size_t)(idx >> 6) * NN + (idx & 63)];
  __syncthreads();
  factor64(T, tid);
  for (int idx = tid; idx < 4096; idx += 256)
    A[(size_t)(idx >> 6) * NN + (idx & 63)] = T[(idx >> 6) * TP + (idx & 63)];
  invert64(T, X, invUb + (size_t)m * 4096, invLb + (size_t)m * 4096, tid);
}

// ---------------- per-iteration step kernel (queue + flags) ----------------

// Consumer-side wait: tid0 spins on device-scope atomics, then a device fence
// (L1/L2 invalidate) before any thread reads the panel outputs.
__device__ __forceinline__ void wait_flags(int* fl, int nl, int* fu, int nu,
                                           int kseq, int tid) {
  if (tid == 0) {
    for (int i = 0; i < nl; ++i)
      while (atomicAdd(fl + i, 0) < kseq) __builtin_amdgcn_s_sleep(2);
    for (int i = 0; i < nu; ++i)
      while (atomicAdd(fu + i, 0) < kseq) __builtin_amdgcn_s_sleep(2);
    __threadfence();
  }
  __syncthreads();
}

__global__ __launch_bounds__(256, 2) void lu_step(float* __restrict__ M,
                                                  float* __restrict__ invU,
                                                  float* __restrict__ invL,
                                                  const int* __restrict__ lengths,
                                                  int* __restrict__ qctr,
                                                  int* __restrict__ Lf,
                                                  int* __restrict__ Uf,
                                                  int k0, int kidx) {
  __shared__ float S[SSZ2];
  __shared__ int Sjob;
  const int tid = threadIdx.x;
  const int kseq = kidx + 1;

  // per-matrix active minor size (round-7 verified decode style)
  int nmr[NMAT];
#pragma unroll
  for (int mm = 0; mm < NMAT; ++mm) {
    int nm = lengths[mm & 3] - 1;
    nm = (nm + 63) & ~63;
    if (nm < 64) nm = 64;
    if (nm > NN) nm = NN;
    nmr[mm] = nm;
  }

  // job counts: panels first, then specials, then regular trails
  int totP = 0, totS = 0, totT = 0;
#pragma unroll
  for (int mm = 0; mm < NMAT; ++mm) {
    int rm = nmr[mm] - k0 - NB;
    if (rm > 0) {
      totP += 2 * (rm >> 6);
      totS += 1;
      int n2 = (rm + 127) >> 7;
      totT += n2 * n2 - 1;
    }
  }
  int totB = totP + totS + totT;

  for (;;) {
    __syncthreads();                       // protect Sjob reuse
    if (tid == 0) Sjob = atomicAdd(&qctr[kidx], 1);
    __syncthreads();
    int job = Sjob;
    if (job >= totB) return;

    if (job < totP) {
      // ---- panel job (no dependencies) ----
      int m = 0, local = 0, bbase = 0;
#pragma unroll
      for (int mm = 0; mm < NMAT; ++mm) {
        int rm = nmr[mm] - k0 - NB;
        int w = rm > 0 ? 2 * (rm >> 6) : 0;
        if (job >= bbase && job < bbase + w) { m = mm; local = job - bbase; }
        bbase += w;
      }
      int npt = (nmr[m] - k0 - NB) >> 6;
      int role = (local >= npt) ? 1 : 0;
      int px = role ? local - npt : local;
      panel_job(M, invU, invL, k0, m, role, px, tid, S);
      __syncthreads();                     // drain all threads' stores (vmcnt)
      if (tid == 0) {
        __threadfence();                   // L2 writeback -> device visibility
        atomicExch(((role == 0) ? Lf : Uf) + m * NCH + px, kseq);
      }
    } else {
      // ---- special (jr < totS) or regular trail tile ----
      int jr = job - totP;
      int m = 0, ty = 0, tx = 0, remm = 64;
      if (jr < totS) {
        int cnt = 0;
#pragma unroll
        for (int mm = 0; mm < NMAT; ++mm) {
          int rm = nmr[mm] - k0 - NB;
          if (rm > 0) { if (cnt == jr) { m = mm; remm = rm; } ++cnt; }
        }
      } else {
        int jt = jr - totS, bbase = 0, tloc = 0;
#pragma unroll
        for (int mm = 0; mm < NMAT; ++mm) {
          int rm = nmr[mm] - k0 - NB;
          int n2 = rm > 0 ? (rm + 127) >> 7 : 0;
          int w = n2 > 0 ? n2 * n2 - 1 : 0;
          if (jt >= bbase && jt < bbase + w) { m = mm; remm = rm; tloc = jt - bbase + 1; }
          bbase += w;
        }
        int n2m = (remm + 127) >> 7;
        ty = tloc / n2m;
        tx = tloc - ty * n2m;
      }
      int nch = remm >> 6;
      wait_flags(Lf + m * NCH + 2 * ty, (2 * ty + 1 < nch) ? 2 : 1,
                 Uf + m * NCH + 2 * tx, (2 * tx + 1 < nch) ? 2 : 1, kseq, tid);
      trail_job(M, invU, invL, k0, remm, m, ty, tx, (remm > 64) ? 1 : 0, tid, S);
    }
  }
}

// ---------------- reduction ----------------

__global__ void logdet_kernel(const float* __restrict__ Mb, double* __restrict__ dlog) {
  int m = blockIdx.x;
  const float* A = Mb + (size_t)m * NN * NN;
  double s = 0.0;
  for (int i = threadIdx.x; i < NN; i += 256)
    s += (double)logf(fabsf(A[(size_t)i * NN + i]));
  __shared__ double red[256];
  red[threadIdx.x] = s;
  __syncthreads();
  for (int k = 128; k > 0; k >>= 1) {
    if (threadIdx.x < k) red[threadIdx.x] += red[threadIdx.x + k];
    __syncthreads();
  }
  if (threadIdx.x == 0) dlog[m] = red[0];
}

__global__ void final_kernel(const double* __restrict__ dlog, float* __restrict__ out) {
  if (threadIdx.x == 0) {
    double acc = 0.0;
    for (int b = 0; b < NBATCH; ++b) acc += dlog[b] - dlog[NBATCH + b];
    out[0] = (float)(acc * 0.25);
  }
}

// ---------------- launch ----------------

extern "C" void kernel_launch(void* const* d_in, const int* in_sizes, int n_in,
                              void* d_out, int out_size, void* d_ws, size_t ws_size,
                              hipStream_t stream) {
  const float* scores  = (const float*)d_in[0];
  const float* tm      = (const float*)d_in[1];  // target_mask
  const float* zm      = (const float*)d_in[2];  // z_mask
  const int*   lengths = (const int*)d_in[3];
  float* out = (float*)d_out;

  // ws layout: M | cs | dlog | invU | invL | qctr | Lf | Uf
  float* M  = (float*)d_ws;
  float* cs = M + (size_t)NMAT * NN * NN;
  double* dlog = (double*)(cs + (size_t)NMAT * NN);
  float* invU = (float*)(dlog + NMAT);
  float* invL = invU + (size_t)NMAT * 4096;
  int* qctr = (int*)(invL + (size_t)NMAT * 4096);
  int* Lf = qctr + NIT;
  int* Uf = Lf + NMAT * NCH;

  init_all<<<(NMAT * NN + 255) / 256, 256, 0, stream>>>(cs, qctr, Lf, Uf);
  build_fused<<<dim3((NN + 255) / 256, NN / 64, NBATCH), 256, 0, stream>>>(
      scores, zm, tm, lengths, cs, M);
  diag_fix<<<(NMAT * NN + 255) / 256, 256, 0, stream>>>(lengths, cs, M);
  factor0<<<NMAT, 256, 0, stream>>>(M, invU, invL);

  int kidx = 0;
  for (int k0 = 0; k0 + NB < NN; k0 += NB, ++kidx) {
    int remX = NN - k0 - NB;                        // worst-case rem (full matrix)
    int n2 = (remX + 127) / 128;
    int tot = NMAT * 2 * (remX / 64) + NMAT * n2 * n2;
    int G = tot < 2048 ? tot : 2048;
    lu_step<<<G, 256, 0, stream>>>(M, invU, invL, lengths, qctr, Lf, Uf, k0, kidx);
  }

  logdet_kernel<<<NMAT, 256, 0, stream>>>(M, dlog);
  final_kernel<<<1, 64, 0, stream>>>(dlog, out);
}